// Round 1
// baseline (584.266 us; speedup 1.0000x reference)
//
#include <hip/hip_runtime.h>
#include <math.h>

#define NN 50000
#define DD 128
#define BN_EPS 1e-5f

// ---------------------------------------------------------------------------
// GEMM: out[which] = X @ W[which] + b[which], tile 64 rows x 128 cols.
// LDS X-tile [64][129] (pad -> conflict-free reads), W streamed from L2.
// ---------------------------------------------------------------------------
__global__ __launch_bounds__(256) void gemm_bias(
    const float* __restrict__ X,
    const float* __restrict__ W0, const float* __restrict__ b0,
    const float* __restrict__ W1, const float* __restrict__ b1,
    const float* __restrict__ W2, const float* __restrict__ b2,
    const float* __restrict__ W3, const float* __restrict__ b3,
    float* __restrict__ out)
{
    __shared__ float xs[64][129];
    const int which = blockIdx.y;
    const float* W  = (which == 0) ? W0 : (which == 1) ? W1 : (which == 2) ? W2 : W3;
    const float* bb = (which == 0) ? b0 : (which == 1) ? b1 : (which == 2) ? b2 : b3;
    float* O = out + (size_t)which * NN * DD;

    const int row0 = blockIdx.x * 64;
    const int tid  = threadIdx.x;

    // stage X tile: 64 rows x 128 cols
    {
        const int rb = tid >> 5;          // 0..7
        const int kq = (tid & 31) * 4;    // 0..124
        #pragma unroll
        for (int it = 0; it < 8; ++it) {
            const int r = rb + it * 8;
            const int row = row0 + r;
            float4 v = make_float4(0.f, 0.f, 0.f, 0.f);
            if (row < NN) v = *(const float4*)(&X[(size_t)row * DD + kq]);
            xs[r][kq + 0] = v.x; xs[r][kq + 1] = v.y;
            xs[r][kq + 2] = v.z; xs[r][kq + 3] = v.w;
        }
    }
    __syncthreads();

    const int tx = tid & 15;   // col group: cols tx*8..+7
    const int ty = tid >> 4;   // row group: rows ty*4..+3

    float acc[4][8];
    #pragma unroll
    for (int i = 0; i < 4; ++i)
        #pragma unroll
        for (int j = 0; j < 8; ++j) acc[i][j] = 0.f;

    #pragma unroll 4
    for (int k = 0; k < 128; ++k) {
        const float4 wa = *(const float4*)(&W[k * DD + tx * 8]);
        const float4 wb = *(const float4*)(&W[k * DD + tx * 8 + 4]);
        float wr[8] = {wa.x, wa.y, wa.z, wa.w, wb.x, wb.y, wb.z, wb.w};
        float xr[4];
        #pragma unroll
        for (int i = 0; i < 4; ++i) xr[i] = xs[ty * 4 + i][k];
        #pragma unroll
        for (int i = 0; i < 4; ++i)
            #pragma unroll
            for (int j = 0; j < 8; ++j)
                acc[i][j] = fmaf(xr[i], wr[j], acc[i][j]);
    }

    const float4 ba = *(const float4*)(&bb[tx * 8]);
    const float4 bc = *(const float4*)(&bb[tx * 8 + 4]);
    #pragma unroll
    for (int i = 0; i < 4; ++i) {
        const int row = row0 + ty * 4 + i;
        if (row < NN) {
            float4 o0 = make_float4(acc[i][0] + ba.x, acc[i][1] + ba.y,
                                    acc[i][2] + ba.z, acc[i][3] + ba.w);
            float4 o1 = make_float4(acc[i][4] + bc.x, acc[i][5] + bc.y,
                                    acc[i][6] + bc.z, acc[i][7] + bc.w);
            *(float4*)(&O[(size_t)row * DD + tx * 8])     = o0;
            *(float4*)(&O[(size_t)row * DD + tx * 8 + 4]) = o1;
        }
    }
}

// ---------------------------------------------------------------------------
// Counting sort of edges by dst
// ---------------------------------------------------------------------------
__global__ void hist_k(const int* __restrict__ dst, int* __restrict__ deg, int ne)
{
    const int e = blockIdx.x * blockDim.x + threadIdx.x;
    if (e < ne) atomicAdd(&deg[dst[e]], 1);
}

__global__ __launch_bounds__(1024) void scan_k(const int* __restrict__ deg,
                                               int* __restrict__ off,
                                               int* __restrict__ cursor)
{
    __shared__ int sd[1024];
    const int t = threadIdx.x;
    const int CH = 49;  // 1024*49 = 50176 >= 50001
    const int beg = t * CH;
    int local = 0;
    for (int i = 0; i < CH; ++i) {
        const int idx = beg + i;
        if (idx < NN) local += deg[idx];
    }
    sd[t] = local;
    __syncthreads();
    for (int o = 1; o < 1024; o <<= 1) {
        int v = (t >= o) ? sd[t - o] : 0;
        __syncthreads();
        sd[t] += v;
        __syncthreads();
    }
    int run = (t == 0) ? 0 : sd[t - 1];
    for (int i = 0; i < CH; ++i) {
        const int idx = beg + i;
        if (idx < NN) {
            off[idx] = run;
            cursor[idx] = run;
            run += deg[idx];
        } else if (idx == NN) {
            off[NN] = run;
        }
    }
}

__global__ void scatter_k(const int* __restrict__ src, const int* __restrict__ dst,
                          int* __restrict__ cursor, int* __restrict__ srt, int ne)
{
    const int e = blockIdx.x * blockDim.x + threadIdx.x;
    if (e < ne) {
        const int p = atomicAdd(&cursor[dst[e]], 1);
        srt[p] = src[e];
    }
}

// ---------------------------------------------------------------------------
// Per-destination-node gate + weighted aggregation + snorm (no float atomics)
// ---------------------------------------------------------------------------
__global__ __launch_bounds__(128) void agg_k(
    const float* __restrict__ AX, const float* __restrict__ BX,
    const float* __restrict__ DX, const float* __restrict__ EX,
    const float* __restrict__ X,
    const int* __restrict__ off, const int* __restrict__ srt,
    float* __restrict__ H)
{
    const int node = blockIdx.x;
    const int t = threadIdx.x;
    const int beg = off[node], end = off[node + 1];
    const float ex = EX[(size_t)node * DD + t];
    float num = 0.f, den = 0.f;
    for (int i = beg; i < end; ++i) {
        const int s = srt[i];
        const float dx = DX[(size_t)s * DD + t];
        const float bx = BX[(size_t)s * DD + t];
        const float sig = 1.0f / (1.0f + __expf(-(dx + ex)));
        num = fmaf(sig, bx, num);
        den += sig;
    }
    float h;
    if (end > beg) h = AX[(size_t)node * DD + t] + num / den;
    else           h = X[(size_t)node * DD + t];
    H[(size_t)node * DD + t] = h * (1.0f / NN);
}

// ---------------------------------------------------------------------------
// BatchNorm column stats (sum, sumsq) -> acc[0..127]=s1, acc[128..255]=s2
// ---------------------------------------------------------------------------
__global__ __launch_bounds__(256) void bnstat_k(const float* __restrict__ H,
                                                float* __restrict__ acc)
{
    __shared__ float l1[256], l2[256];
    const int t = threadIdx.x;
    const int f = t & 127, g = t >> 7;
    const int n0 = blockIdx.x * 125;
    float s1 = 0.f, s2 = 0.f;
    for (int r = g; r < 125; r += 2) {
        const float h = H[(size_t)(n0 + r) * DD + f];
        s1 += h;
        s2 += h * h;
    }
    l1[t] = s1; l2[t] = s2;
    __syncthreads();
    if (t < 128) {
        s1 = l1[t] + l1[t + 128];
        s2 = l2[t] + l2[t + 128];
        atomicAdd(&acc[f], s1);
        atomicAdd(&acc[128 + f], s2);
    }
}

// ---------------------------------------------------------------------------
// Final: out = X + relu(BN(H))
// ---------------------------------------------------------------------------
__global__ __launch_bounds__(256) void final_k(
    const float* __restrict__ H, const float* __restrict__ X,
    const float* __restrict__ acc,
    const float* __restrict__ gamma, const float* __restrict__ beta,
    float* __restrict__ out)
{
    const int i = blockIdx.x * 256 + threadIdx.x;
    if (i >= NN * DD) return;
    const int f = i & 127;
    const float mean = acc[f] * (1.0f / NN);
    const float var  = acc[128 + f] * (1.0f / NN) - mean * mean;
    const float rstd = rsqrtf(var + BN_EPS);
    float v = (H[i] - mean) * rstd * gamma[f] + beta[f];
    v = fmaxf(v, 0.f);
    out[i] = X[i] + v;
}

// ---------------------------------------------------------------------------
extern "C" void kernel_launch(void* const* d_in, const int* in_sizes, int n_in,
                              void* d_out, int out_size, void* d_ws, size_t ws_size,
                              hipStream_t stream)
{
    const float* X     = (const float*)d_in[0];
    const float* W_A   = (const float*)d_in[1];
    const float* b_A   = (const float*)d_in[2];
    const float* W_B   = (const float*)d_in[3];
    const float* b_B   = (const float*)d_in[4];
    const float* W_D   = (const float*)d_in[5];
    const float* b_D   = (const float*)d_in[6];
    const float* W_E   = (const float*)d_in[7];
    const float* b_E   = (const float*)d_in[8];
    const float* gamma = (const float*)d_in[9];
    const float* beta  = (const float*)d_in[10];
    const int*   src   = (const int*)d_in[11];
    const int*   dst   = (const int*)d_in[12];
    const int    ne    = in_sizes[11];
    float* out = (float*)d_out;

    // workspace layout
    char* w = (char*)d_ws;
    const size_t ndf = (size_t)NN * DD * sizeof(float);
    float* PROJ = (float*)w;                 w += 4 * ndf;   // AX,BX,DX,EX
    float* AX = PROJ;
    float* BX = PROJ + (size_t)NN * DD;
    float* DX = PROJ + 2 * (size_t)NN * DD;
    float* EX = PROJ + 3 * (size_t)NN * DD;
    float* H  = (float*)w;                   w += ndf;
    float* acc = (float*)w;                  w += 256 * sizeof(float);
    int* deg    = (int*)w;                   w += (size_t)NN * sizeof(int);
    int* off    = (int*)w;                   w += (size_t)(NN + 1) * sizeof(int);
    int* cursor = (int*)w;                   w += (size_t)NN * sizeof(int);
    int* srt    = (int*)w;                   w += (size_t)ne * sizeof(int);

    hipMemsetAsync(deg, 0, (size_t)NN * sizeof(int), stream);
    hipMemsetAsync(acc, 0, 256 * sizeof(float), stream);

    // 1) projections
    dim3 ggrid((NN + 63) / 64, 4);
    gemm_bias<<<ggrid, 256, 0, stream>>>(X, W_A, b_A, W_B, b_B, W_D, b_D, W_E, b_E, PROJ);

    // 2) counting sort by dst
    hist_k<<<(ne + 255) / 256, 256, 0, stream>>>(dst, deg, ne);
    scan_k<<<1, 1024, 0, stream>>>(deg, off, cursor);
    scatter_k<<<(ne + 255) / 256, 256, 0, stream>>>(src, dst, cursor, srt, ne);

    // 3) gate + aggregation + snorm
    agg_k<<<NN, 128, 0, stream>>>(AX, BX, DX, EX, X, off, srt, H);

    // 4) BN stats
    bnstat_k<<<400, 256, 0, stream>>>(H, acc);

    // 5) final
    final_k<<<(NN * DD + 255) / 256, 256, 0, stream>>>(H, X, acc, gamma, beta, out);
}

// Round 2
// 516.137 us; speedup vs baseline: 1.1320x; 1.1320x over previous
//
#include <hip/hip_runtime.h>
#include <hip/hip_bf16.h>
#include <math.h>

#define NN 50000
#define DD 128
#define BN_EPS 1e-5f

typedef short short8 __attribute__((ext_vector_type(8)));
typedef float f32x4 __attribute__((ext_vector_type(4)));

__device__ __forceinline__ unsigned short f2bf(float f) {
    __hip_bfloat16 h = __float2bfloat16(f);
    return *reinterpret_cast<unsigned short*>(&h);
}

// ---------------------------------------------------------------------------
// Prep: Wt[which][col][k] bf16 (transposed W), row-major 128x128 per which.
// ---------------------------------------------------------------------------
__global__ __launch_bounds__(256) void prep_w(
    const float* __restrict__ W0, const float* __restrict__ W1,
    const float* __restrict__ W2, const float* __restrict__ W3,
    unsigned short* __restrict__ Wt)
{
    const int which = blockIdx.x;
    const float* W = (which == 0) ? W0 : (which == 1) ? W1 : (which == 2) ? W2 : W3;
    unsigned short* O = Wt + (size_t)which * 16384;
    for (int it = 0; it < 8; ++it) {
        const int id = it * 256 + threadIdx.x;   // 0..2047
        const int col = id >> 4;                 // 0..127
        const int kc  = id & 15;                 // 0..15 (8 k each)
        unsigned int pk[4];
        #pragma unroll
        for (int p = 0; p < 4; ++p) {
            const float f0 = W[(kc * 8 + p * 2 + 0) * DD + col];
            const float f1 = W[(kc * 8 + p * 2 + 1) * DD + col];
            pk[p] = (unsigned int)f2bf(f0) | ((unsigned int)f2bf(f1) << 16);
        }
        uint4 v = make_uint4(pk[0], pk[1], pk[2], pk[3]);
        *(uint4*)(O + col * 128 + kc * 8) = v;
    }
}

// ---------------------------------------------------------------------------
// Fused 4-projection MFMA GEMM. Block = 64 rows of X (bf16 in swizzled LDS),
// wave w computes projection w: 0->AX(f32), 1->B half of BD(bf16),
// 2->D half of BD(bf16), 3->EX(f32).
// ---------------------------------------------------------------------------
__global__ __launch_bounds__(256) void gemm4(
    const float* __restrict__ X, const unsigned short* __restrict__ Wt,
    const float* __restrict__ bA, const float* __restrict__ bB,
    const float* __restrict__ bD, const float* __restrict__ bE,
    float* __restrict__ AX, float* __restrict__ EX,
    unsigned short* __restrict__ BD)
{
    __shared__ char xs[64 * 256];   // 64 rows x 128 bf16, XOR-swizzled
    const int row0 = blockIdx.x * 64;
    const int tid  = threadIdx.x;

    // stage + convert X tile
    {
        const int r  = tid >> 2;        // 0..63
        const int pq = tid & 3;         // 128B part of the row
        const bool valid = (row0 + r) < NN;
        const float* gp = X + (size_t)(row0 + r) * DD + pq * 32;
        #pragma unroll
        for (int i = 0; i < 4; ++i) {
            float4 va = make_float4(0.f, 0.f, 0.f, 0.f);
            float4 vb = make_float4(0.f, 0.f, 0.f, 0.f);
            if (valid) {
                va = *(const float4*)(gp + i * 8);
                vb = *(const float4*)(gp + i * 8 + 4);
            }
            uint4 pk;
            pk.x = (unsigned int)f2bf(va.x) | ((unsigned int)f2bf(va.y) << 16);
            pk.y = (unsigned int)f2bf(va.z) | ((unsigned int)f2bf(va.w) << 16);
            pk.z = (unsigned int)f2bf(vb.x) | ((unsigned int)f2bf(vb.y) << 16);
            pk.w = (unsigned int)f2bf(vb.z) | ((unsigned int)f2bf(vb.w) << 16);
            const int c = pq * 4 + i;   // 16B chunk index 0..15
            *(uint4*)(xs + r * 256 + ((c * 16) ^ ((r & 7) << 4))) = pk;
        }
    }
    __syncthreads();

    const int wid  = tid >> 6;          // which projection
    const int lane = tid & 63;
    const int lr = lane & 15, lg = lane >> 4;

    f32x4 acc[4][8];
    #pragma unroll
    for (int m = 0; m < 4; ++m)
        #pragma unroll
        for (int n = 0; n < 8; ++n)
            acc[m][n] = (f32x4){0.f, 0.f, 0.f, 0.f};

    const char* wb = (const char*)(Wt + (size_t)wid * 16384);

    #pragma unroll
    for (int k = 0; k < 4; ++k) {
        short8 bf[8];
        #pragma unroll
        for (int n = 0; n < 8; ++n)
            bf[n] = *(const short8*)(wb + (n * 16 + lr) * 256 + k * 64 + lg * 16);
        short8 af[4];
        #pragma unroll
        for (int m = 0; m < 4; ++m) {
            const int row = m * 16 + lr;
            af[m] = *(const short8*)(xs + row * 256 +
                                     ((k * 64 + lg * 16) ^ ((row & 7) << 4)));
        }
        #pragma unroll
        for (int m = 0; m < 4; ++m)
            #pragma unroll
            for (int n = 0; n < 8; ++n)
                acc[m][n] = __builtin_amdgcn_mfma_f32_16x16x32_bf16(
                    af[m], bf[n], acc[m][n], 0, 0, 0);
    }

    const float* bias = (wid == 0) ? bA : (wid == 1) ? bB : (wid == 2) ? bD : bE;
    #pragma unroll
    for (int n = 0; n < 8; ++n) {
        const int col = n * 16 + lr;
        const float bv = bias[col];
        #pragma unroll
        for (int m = 0; m < 4; ++m) {
            #pragma unroll
            for (int q = 0; q < 4; ++q) {
                const int row = row0 + m * 16 + lg * 4 + q;
                if (row < NN) {
                    const float v = acc[m][n][q] + bv;
                    if (wid == 0)      AX[(size_t)row * DD + col] = v;
                    else if (wid == 3) EX[(size_t)row * DD + col] = v;
                    else BD[(size_t)row * 256 + (wid == 2 ? 128 : 0) + col] = f2bf(v);
                }
            }
        }
    }
}

// ---------------------------------------------------------------------------
// Counting sort of edges by dst
// ---------------------------------------------------------------------------
__global__ void hist_k(const int* __restrict__ dst, int* __restrict__ deg, int ne)
{
    const int e = blockIdx.x * blockDim.x + threadIdx.x;
    if (e < ne) atomicAdd(&deg[dst[e]], 1);
}

__global__ __launch_bounds__(1024) void scan_k(const int* __restrict__ deg,
                                               int* __restrict__ off,
                                               int* __restrict__ cursor)
{
    __shared__ int sd[1024];
    const int t = threadIdx.x;
    const int CH = 49;  // 1024*49 = 50176 >= 50001
    const int beg = t * CH;
    int local = 0;
    for (int i = 0; i < CH; ++i) {
        const int idx = beg + i;
        if (idx < NN) local += deg[idx];
    }
    sd[t] = local;
    __syncthreads();
    for (int o = 1; o < 1024; o <<= 1) {
        int v = (t >= o) ? sd[t - o] : 0;
        __syncthreads();
        sd[t] += v;
        __syncthreads();
    }
    int run = (t == 0) ? 0 : sd[t - 1];
    for (int i = 0; i < CH; ++i) {
        const int idx = beg + i;
        if (idx < NN) {
            off[idx] = run;
            cursor[idx] = run;
            run += deg[idx];
        } else if (idx == NN) {
            off[NN] = run;
        }
    }
}

__global__ void scatter_k(const int* __restrict__ src, const int* __restrict__ dst,
                          int* __restrict__ cursor, int* __restrict__ srt, int ne)
{
    const int e = blockIdx.x * blockDim.x + threadIdx.x;
    if (e < ne) {
        const int p = atomicAdd(&cursor[dst[e]], 1);
        srt[p] = src[e];
    }
}

// ---------------------------------------------------------------------------
// Gate + weighted aggregation + snorm. One WAVE per node, 2 features/lane.
// BD row (bf16): [0..127]=B, [128..255]=D  (=128 dwords).
// ---------------------------------------------------------------------------
__global__ __launch_bounds__(256) void agg_k(
    const float* __restrict__ AX, const float* __restrict__ EX,
    const unsigned int* __restrict__ BDu, const float* __restrict__ X,
    const int* __restrict__ off, const int* __restrict__ srt,
    float* __restrict__ H)
{
    const int wid  = threadIdx.x >> 6;
    const int lane = threadIdx.x & 63;
    const int node = blockIdx.x * 4 + wid;
    const int beg = off[node], end = off[node + 1];

    const float2 ex = *(const float2*)(EX + (size_t)node * DD + lane * 2);
    float nlo = 0.f, nhi = 0.f, dlo = 0.f, dhi = 0.f;

#define EDGE(bw, dw)                                                         \
    {                                                                        \
        const float blo_ = __uint_as_float((bw) << 16);                      \
        const float bhi_ = __uint_as_float((bw) & 0xffff0000u);              \
        const float dlo_ = __uint_as_float((dw) << 16);                      \
        const float dhi_ = __uint_as_float((dw) & 0xffff0000u);              \
        const float slo_ = 1.0f / (1.0f + __expf(-(dlo_ + ex.x)));           \
        const float shi_ = 1.0f / (1.0f + __expf(-(dhi_ + ex.y)));           \
        nlo = fmaf(slo_, blo_, nlo);                                         \
        nhi = fmaf(shi_, bhi_, nhi);                                         \
        dlo += slo_;                                                         \
        dhi += shi_;                                                         \
    }

    int i = beg;
    for (; i + 4 <= end; i += 4) {
        const int s0 = srt[i], s1 = srt[i + 1], s2 = srt[i + 2], s3 = srt[i + 3];
        const unsigned int b0 = BDu[(size_t)s0 * 128 + lane];
        const unsigned int d0 = BDu[(size_t)s0 * 128 + 64 + lane];
        const unsigned int b1 = BDu[(size_t)s1 * 128 + lane];
        const unsigned int d1 = BDu[(size_t)s1 * 128 + 64 + lane];
        const unsigned int b2 = BDu[(size_t)s2 * 128 + lane];
        const unsigned int d2 = BDu[(size_t)s2 * 128 + 64 + lane];
        const unsigned int b3 = BDu[(size_t)s3 * 128 + lane];
        const unsigned int d3 = BDu[(size_t)s3 * 128 + 64 + lane];
        EDGE(b0, d0); EDGE(b1, d1); EDGE(b2, d2); EDGE(b3, d3);
    }
    for (; i < end; ++i) {
        const int s = srt[i];
        const unsigned int b = BDu[(size_t)s * 128 + lane];
        const unsigned int d = BDu[(size_t)s * 128 + 64 + lane];
        EDGE(b, d);
    }
#undef EDGE

    float2 h;
    if (end > beg) {
        const float2 ax = *(const float2*)(AX + (size_t)node * DD + lane * 2);
        h.x = ax.x + nlo / dlo;
        h.y = ax.y + nhi / dhi;
    } else {
        h = *(const float2*)(X + (size_t)node * DD + lane * 2);
    }
    h.x *= (1.0f / NN);
    h.y *= (1.0f / NN);
    *(float2*)(H + (size_t)node * DD + lane * 2) = h;
}

// ---------------------------------------------------------------------------
// BatchNorm column stats (sum, sumsq) -> acc[0..127]=s1, acc[128..255]=s2
// ---------------------------------------------------------------------------
__global__ __launch_bounds__(256) void bnstat_k(const float* __restrict__ H,
                                                float* __restrict__ acc)
{
    __shared__ float l1[256], l2[256];
    const int t = threadIdx.x;
    const int f = t & 127, g = t >> 7;
    const int n0 = blockIdx.x * 125;
    float s1 = 0.f, s2 = 0.f;
    for (int r = g; r < 125; r += 2) {
        const float h = H[(size_t)(n0 + r) * DD + f];
        s1 += h;
        s2 += h * h;
    }
    l1[t] = s1; l2[t] = s2;
    __syncthreads();
    if (t < 128) {
        s1 = l1[t] + l1[t + 128];
        s2 = l2[t] + l2[t + 128];
        atomicAdd(&acc[f], s1);
        atomicAdd(&acc[128 + f], s2);
    }
}

// ---------------------------------------------------------------------------
// Final: out = X + relu(BN(H)), float4 per thread.
// ---------------------------------------------------------------------------
__global__ __launch_bounds__(256) void final_k(
    const float* __restrict__ H, const float* __restrict__ X,
    const float* __restrict__ acc,
    const float* __restrict__ gamma, const float* __restrict__ beta,
    float* __restrict__ out)
{
    const int i = blockIdx.x * 256 + threadIdx.x;
    if (i >= NN * 32) return;
    const int f = (i & 31) * 4;
    const float4 h = *(const float4*)(H + (size_t)i * 4);
    const float4 x = *(const float4*)(X + (size_t)i * 4);
    float4 o;
    #pragma unroll
    for (int c = 0; c < 4; ++c) {
        const float mean = acc[f + c] * (1.0f / NN);
        const float var  = acc[128 + f + c] * (1.0f / NN) - mean * mean;
        const float rstd = rsqrtf(var + BN_EPS);
        const float hv = (c == 0) ? h.x : (c == 1) ? h.y : (c == 2) ? h.z : h.w;
        const float xv = (c == 0) ? x.x : (c == 1) ? x.y : (c == 2) ? x.z : x.w;
        float v = (hv - mean) * rstd * gamma[f + c] + beta[f + c];
        v = fmaxf(v, 0.f);
        const float r = xv + v;
        if (c == 0) o.x = r; else if (c == 1) o.y = r; else if (c == 2) o.z = r; else o.w = r;
    }
    *(float4*)(out + (size_t)i * 4) = o;
}

// ---------------------------------------------------------------------------
extern "C" void kernel_launch(void* const* d_in, const int* in_sizes, int n_in,
                              void* d_out, int out_size, void* d_ws, size_t ws_size,
                              hipStream_t stream)
{
    const float* X     = (const float*)d_in[0];
    const float* W_A   = (const float*)d_in[1];
    const float* b_A   = (const float*)d_in[2];
    const float* W_B   = (const float*)d_in[3];
    const float* b_B   = (const float*)d_in[4];
    const float* W_D   = (const float*)d_in[5];
    const float* b_D   = (const float*)d_in[6];
    const float* W_E   = (const float*)d_in[7];
    const float* b_E   = (const float*)d_in[8];
    const float* gamma = (const float*)d_in[9];
    const float* beta  = (const float*)d_in[10];
    const int*   src   = (const int*)d_in[11];
    const int*   dst   = (const int*)d_in[12];
    const int    ne    = in_sizes[11];
    float* out = (float*)d_out;

    // workspace layout
    char* w = (char*)d_ws;
    const size_t ndf = (size_t)NN * DD * sizeof(float);
    unsigned short* Wt = (unsigned short*)w;  w += 4 * 16384 * sizeof(unsigned short);
    float* AX = (float*)w;                    w += ndf;
    float* EX = (float*)w;                    w += ndf;
    unsigned short* BD = (unsigned short*)w;  w += (size_t)NN * 256 * sizeof(unsigned short);
    float* H  = (float*)w;                    w += ndf;
    float* acc = (float*)w;                   w += 256 * sizeof(float);
    int* deg    = (int*)w;                    w += (size_t)NN * sizeof(int);
    int* off    = (int*)w;                    w += (size_t)(NN + 4) * sizeof(int);
    int* cursor = (int*)w;                    w += (size_t)NN * sizeof(int);
    int* srt    = (int*)w;                    w += (size_t)ne * sizeof(int);

    hipMemsetAsync(deg, 0, (size_t)NN * sizeof(int), stream);
    hipMemsetAsync(acc, 0, 256 * sizeof(float), stream);

    // weight prep + counting sort (independent of GEMM)
    prep_w<<<4, 256, 0, stream>>>(W_A, W_B, W_D, W_E, Wt);
    hist_k<<<(ne + 255) / 256, 256, 0, stream>>>(dst, deg, ne);
    scan_k<<<1, 1024, 0, stream>>>(deg, off, cursor);

    // fused 4-projection GEMM
    gemm4<<<(NN + 63) / 64, 256, 0, stream>>>(X, Wt, b_A, b_B, b_D, b_E, AX, EX, BD);

    scatter_k<<<(ne + 255) / 256, 256, 0, stream>>>(src, dst, cursor, srt, ne);

    // gate + aggregation + snorm (one wave per node)
    agg_k<<<NN / 4, 256, 0, stream>>>(AX, EX, (const unsigned int*)BD, X, off, srt, H);

    // BN stats
    bnstat_k<<<400, 256, 0, stream>>>(H, acc);

    // final
    final_k<<<(NN * 32 + 255) / 256, 256, 0, stream>>>(H, X, acc, gamma, beta, out);
}

// Round 3
// 395.125 us; speedup vs baseline: 1.4787x; 1.3063x over previous
//
#include <hip/hip_runtime.h>
#include <hip/hip_bf16.h>
#include <math.h>

#define NN 50000
#define DD 128
#define BN_EPS 1e-5f
#define SCAN_NB 49   // 49*1024 = 50176 >= NN

typedef short short8 __attribute__((ext_vector_type(8)));
typedef float f32x4 __attribute__((ext_vector_type(4)));

__device__ __forceinline__ unsigned short f2bf(float f) {
    __hip_bfloat16 h = __float2bfloat16(f);
    return *reinterpret_cast<unsigned short*>(&h);
}

// ---------------------------------------------------------------------------
// Prep: Wt[which][col][k] bf16 (transposed W), row-major 128x128 per which.
// ---------------------------------------------------------------------------
__global__ __launch_bounds__(256) void prep_w(
    const float* __restrict__ W0, const float* __restrict__ W1,
    const float* __restrict__ W2, const float* __restrict__ W3,
    unsigned short* __restrict__ Wt)
{
    const int which = blockIdx.x;
    const float* W = (which == 0) ? W0 : (which == 1) ? W1 : (which == 2) ? W2 : W3;
    unsigned short* O = Wt + (size_t)which * 16384;
    for (int it = 0; it < 8; ++it) {
        const int id = it * 256 + threadIdx.x;   // 0..2047
        const int col = id >> 4;                 // 0..127
        const int kc  = id & 15;                 // 0..15 (8 k each)
        unsigned int pk[4];
        #pragma unroll
        for (int p = 0; p < 4; ++p) {
            const float f0 = W[(kc * 8 + p * 2 + 0) * DD + col];
            const float f1 = W[(kc * 8 + p * 2 + 1) * DD + col];
            pk[p] = (unsigned int)f2bf(f0) | ((unsigned int)f2bf(f1) << 16);
        }
        uint4 v = make_uint4(pk[0], pk[1], pk[2], pk[3]);
        *(uint4*)(O + col * 128 + kc * 8) = v;
    }
}

// ---------------------------------------------------------------------------
// Fused 4-projection MFMA GEMM. Block = 64 rows of X (bf16 in swizzled LDS),
// wave w computes projection w: 0->AX(f32), 1->B half of BD(bf16),
// 2->D half of BD(bf16), 3->EX(f32).
// BD row layout (shorts): pair p: [4p]=b(2p) [4p+1]=b(2p+1) [4p+2]=d(2p) [4p+3]=d(2p+1)
// ---------------------------------------------------------------------------
__global__ __launch_bounds__(256) void gemm4(
    const float* __restrict__ X, const unsigned short* __restrict__ Wt,
    const float* __restrict__ bA, const float* __restrict__ bB,
    const float* __restrict__ bD, const float* __restrict__ bE,
    float* __restrict__ AX, float* __restrict__ EX,
    unsigned short* __restrict__ BD)
{
    __shared__ char xs[64 * 256];   // 64 rows x 128 bf16, XOR-swizzled
    const int row0 = blockIdx.x * 64;
    const int tid  = threadIdx.x;

    // stage + convert X tile
    {
        const int r  = tid >> 2;        // 0..63
        const int pq = tid & 3;         // 128B part of the row
        const bool valid = (row0 + r) < NN;
        const float* gp = X + (size_t)(row0 + r) * DD + pq * 32;
        #pragma unroll
        for (int i = 0; i < 4; ++i) {
            float4 va = make_float4(0.f, 0.f, 0.f, 0.f);
            float4 vb = make_float4(0.f, 0.f, 0.f, 0.f);
            if (valid) {
                va = *(const float4*)(gp + i * 8);
                vb = *(const float4*)(gp + i * 8 + 4);
            }
            uint4 pk;
            pk.x = (unsigned int)f2bf(va.x) | ((unsigned int)f2bf(va.y) << 16);
            pk.y = (unsigned int)f2bf(va.z) | ((unsigned int)f2bf(va.w) << 16);
            pk.z = (unsigned int)f2bf(vb.x) | ((unsigned int)f2bf(vb.y) << 16);
            pk.w = (unsigned int)f2bf(vb.z) | ((unsigned int)f2bf(vb.w) << 16);
            const int c = pq * 4 + i;   // 16B chunk index 0..15
            *(uint4*)(xs + r * 256 + ((c * 16) ^ ((r & 7) << 4))) = pk;
        }
    }
    __syncthreads();

    const int wid  = tid >> 6;          // which projection
    const int lane = tid & 63;
    const int lr = lane & 15, lg = lane >> 4;

    f32x4 acc[4][8];
    #pragma unroll
    for (int m = 0; m < 4; ++m)
        #pragma unroll
        for (int n = 0; n < 8; ++n)
            acc[m][n] = (f32x4){0.f, 0.f, 0.f, 0.f};

    const char* wb = (const char*)(Wt + (size_t)wid * 16384);

    #pragma unroll
    for (int k = 0; k < 4; ++k) {
        short8 bf[8];
        #pragma unroll
        for (int n = 0; n < 8; ++n)
            bf[n] = *(const short8*)(wb + (n * 16 + lr) * 256 + k * 64 + lg * 16);
        short8 af[4];
        #pragma unroll
        for (int m = 0; m < 4; ++m) {
            const int row = m * 16 + lr;
            af[m] = *(const short8*)(xs + row * 256 +
                                     ((k * 64 + lg * 16) ^ ((row & 7) << 4)));
        }
        #pragma unroll
        for (int m = 0; m < 4; ++m)
            #pragma unroll
            for (int n = 0; n < 8; ++n)
                acc[m][n] = __builtin_amdgcn_mfma_f32_16x16x32_bf16(
                    af[m], bf[n], acc[m][n], 0, 0, 0);
    }

    const float* bias = (wid == 0) ? bA : (wid == 1) ? bB : (wid == 2) ? bD : bE;
    #pragma unroll
    for (int n = 0; n < 8; ++n) {
        const int col = n * 16 + lr;
        const float bv = bias[col];
        #pragma unroll
        for (int m = 0; m < 4; ++m) {
            #pragma unroll
            for (int q = 0; q < 4; ++q) {
                const int row = row0 + m * 16 + lg * 4 + q;
                if (row < NN) {
                    const float v = acc[m][n][q] + bv;
                    if (wid == 0)      AX[(size_t)row * DD + col] = v;
                    else if (wid == 3) EX[(size_t)row * DD + col] = v;
                    else {
                        // interleaved pair layout
                        const int o = (col >> 1) * 4 + ((wid == 2) ? 2 : 0) + (col & 1);
                        BD[(size_t)row * 256 + o] = f2bf(v);
                    }
                }
            }
        }
    }
}

// ---------------------------------------------------------------------------
// Counting sort of edges by dst
// ---------------------------------------------------------------------------
__global__ void hist_k(const int* __restrict__ dst, int* __restrict__ deg, int ne)
{
    const int e = blockIdx.x * blockDim.x + threadIdx.x;
    if (e < ne) atomicAdd(&deg[dst[e]], 1);
}

// 3-kernel scan: per-block sums -> scan of sums -> per-element offsets
__global__ __launch_bounds__(1024) void partial_k(const int* __restrict__ deg,
                                                  int* __restrict__ bsum)
{
    __shared__ int ls[16];
    const int idx = blockIdx.x * 1024 + threadIdx.x;
    int v = (idx < NN) ? deg[idx] : 0;
    #pragma unroll
    for (int o = 1; o < 64; o <<= 1) v += __shfl_xor(v, o, 64);
    if ((threadIdx.x & 63) == 0) ls[threadIdx.x >> 6] = v;
    __syncthreads();
    if (threadIdx.x == 0) {
        int s = 0;
        #pragma unroll
        for (int i = 0; i < 16; ++i) s += ls[i];
        bsum[blockIdx.x] = s;
    }
}

__global__ __launch_bounds__(64) void scanblk_k(const int* __restrict__ bsum,
                                                int* __restrict__ bbase,
                                                int* __restrict__ off)
{
    const int t = threadIdx.x;
    int v = (t < SCAN_NB) ? bsum[t] : 0;
    const int orig = v;
    #pragma unroll
    for (int o = 1; o < 64; o <<= 1) {
        const int u = __shfl_up(v, o, 64);
        if (t >= o) v += u;
    }
    if (t < SCAN_NB) bbase[t] = v - orig;
    if (t == 63) off[NN] = v;   // grand total
}

__global__ __launch_bounds__(1024) void offs_k(const int* __restrict__ deg,
                                               const int* __restrict__ bbase,
                                               int* __restrict__ off,
                                               int* __restrict__ cursor)
{
    __shared__ int ws[16];
    const int idx = blockIdx.x * 1024 + threadIdx.x;
    const int t = threadIdx.x;
    int v = (idx < NN) ? deg[idx] : 0;
    const int orig = v;
    #pragma unroll
    for (int o = 1; o < 64; o <<= 1) {
        const int u = __shfl_up(v, o, 64);
        if ((t & 63) >= o) v += u;
    }
    if ((t & 63) == 63) ws[t >> 6] = v;
    __syncthreads();
    int base = 0;
    for (int i = 0; i < (t >> 6); ++i) base += ws[i];
    const int ex = bbase[blockIdx.x] + base + (v - orig);
    if (idx < NN) { off[idx] = ex; cursor[idx] = ex; }
}

__global__ void scatter_k(const int* __restrict__ src, const int* __restrict__ dst,
                          int* __restrict__ cursor, int* __restrict__ srt, int ne)
{
    const int e = blockIdx.x * blockDim.x + threadIdx.x;
    if (e < ne) {
        const int p = atomicAdd(&cursor[dst[e]], 1);
        srt[p] = src[e];
    }
}

// ---------------------------------------------------------------------------
// Gate + weighted aggregation + snorm. One WAVE per node, 2 features/lane.
// BD row = 64 uint2/wave-lane: .x = b-pair, .y = d-pair for features 2L,2L+1.
// ---------------------------------------------------------------------------
__global__ __launch_bounds__(256) void agg_k(
    const float* __restrict__ AX, const float* __restrict__ EX,
    const uint2* __restrict__ BD2, const float* __restrict__ X,
    const int* __restrict__ off, const int* __restrict__ srt,
    float* __restrict__ H)
{
    const int wid  = threadIdx.x >> 6;
    const int lane = threadIdx.x & 63;
    const int node = blockIdx.x * 4 + wid;
    const int beg = off[node], end = off[node + 1];

    const float2 ex = *(const float2*)(EX + (size_t)node * DD + lane * 2);
    float nlo = 0.f, nhi = 0.f, dlo = 0.f, dhi = 0.f;

#define EDGE(bw, dw)                                                         \
    {                                                                        \
        const float blo_ = __uint_as_float((bw) << 16);                      \
        const float bhi_ = __uint_as_float((bw) & 0xffff0000u);              \
        const float dlo_ = __uint_as_float((dw) << 16);                      \
        const float dhi_ = __uint_as_float((dw) & 0xffff0000u);              \
        const float slo_ = 1.0f / (1.0f + __expf(-(dlo_ + ex.x)));           \
        const float shi_ = 1.0f / (1.0f + __expf(-(dhi_ + ex.y)));           \
        nlo = fmaf(slo_, blo_, nlo);                                         \
        nhi = fmaf(shi_, bhi_, nhi);                                         \
        dlo += slo_;                                                         \
        dhi += shi_;                                                         \
    }

    int i = beg;
    for (; i + 8 <= end; i += 8) {
        int ss[8];
        #pragma unroll
        for (int u = 0; u < 8; ++u) ss[u] = srt[i + u];
        uint2 wv[8];
        #pragma unroll
        for (int u = 0; u < 8; ++u) wv[u] = BD2[(size_t)ss[u] * 64 + lane];
        #pragma unroll
        for (int u = 0; u < 8; ++u) EDGE(wv[u].x, wv[u].y);
    }
    for (; i < end; ++i) {
        const int s = srt[i];
        const uint2 w = BD2[(size_t)s * 64 + lane];
        EDGE(w.x, w.y);
    }
#undef EDGE

    float2 h;
    if (end > beg) {
        const float2 ax = *(const float2*)(AX + (size_t)node * DD + lane * 2);
        h.x = ax.x + nlo / dlo;
        h.y = ax.y + nhi / dhi;
    } else {
        h = *(const float2*)(X + (size_t)node * DD + lane * 2);
    }
    h.x *= (1.0f / NN);
    h.y *= (1.0f / NN);
    *(float2*)(H + (size_t)node * DD + lane * 2) = h;
}

// ---------------------------------------------------------------------------
// BatchNorm column stats (sum, sumsq) -> acc[0..127]=s1, acc[128..255]=s2
// ---------------------------------------------------------------------------
__global__ __launch_bounds__(256) void bnstat_k(const float* __restrict__ H,
                                                float* __restrict__ acc)
{
    __shared__ float l1[256], l2[256];
    const int t = threadIdx.x;
    const int f = t & 127, g = t >> 7;
    const int n0 = blockIdx.x * 125;
    float s1 = 0.f, s2 = 0.f;
    for (int r = g; r < 125; r += 2) {
        const float h = H[(size_t)(n0 + r) * DD + f];
        s1 += h;
        s2 += h * h;
    }
    l1[t] = s1; l2[t] = s2;
    __syncthreads();
    if (t < 128) {
        s1 = l1[t] + l1[t + 128];
        s2 = l2[t] + l2[t + 128];
        atomicAdd(&acc[f], s1);
        atomicAdd(&acc[128 + f], s2);
    }
}

// ---------------------------------------------------------------------------
// Final: out = X + relu(BN(H)), float4 per thread.
// ---------------------------------------------------------------------------
__global__ __launch_bounds__(256) void final_k(
    const float* __restrict__ H, const float* __restrict__ X,
    const float* __restrict__ acc,
    const float* __restrict__ gamma, const float* __restrict__ beta,
    float* __restrict__ out)
{
    const int i = blockIdx.x * 256 + threadIdx.x;
    if (i >= NN * 32) return;
    const int f = (i & 31) * 4;
    const float4 h = *(const float4*)(H + (size_t)i * 4);
    const float4 x = *(const float4*)(X + (size_t)i * 4);
    float4 o;
    #pragma unroll
    for (int c = 0; c < 4; ++c) {
        const float mean = acc[f + c] * (1.0f / NN);
        const float var  = acc[128 + f + c] * (1.0f / NN) - mean * mean;
        const float rstd = rsqrtf(var + BN_EPS);
        const float hv = (c == 0) ? h.x : (c == 1) ? h.y : (c == 2) ? h.z : h.w;
        const float xv = (c == 0) ? x.x : (c == 1) ? x.y : (c == 2) ? x.z : x.w;
        float v = (hv - mean) * rstd * gamma[f + c] + beta[f + c];
        v = fmaxf(v, 0.f);
        const float r = xv + v;
        if (c == 0) o.x = r; else if (c == 1) o.y = r; else if (c == 2) o.z = r; else o.w = r;
    }
    *(float4*)(out + (size_t)i * 4) = o;
}

// ---------------------------------------------------------------------------
extern "C" void kernel_launch(void* const* d_in, const int* in_sizes, int n_in,
                              void* d_out, int out_size, void* d_ws, size_t ws_size,
                              hipStream_t stream)
{
    const float* X     = (const float*)d_in[0];
    const float* W_A   = (const float*)d_in[1];
    const float* b_A   = (const float*)d_in[2];
    const float* W_B   = (const float*)d_in[3];
    const float* b_B   = (const float*)d_in[4];
    const float* W_D   = (const float*)d_in[5];
    const float* b_D   = (const float*)d_in[6];
    const float* W_E   = (const float*)d_in[7];
    const float* b_E   = (const float*)d_in[8];
    const float* gamma = (const float*)d_in[9];
    const float* beta  = (const float*)d_in[10];
    const int*   src   = (const int*)d_in[11];
    const int*   dst   = (const int*)d_in[12];
    const int    ne    = in_sizes[11];
    float* out = (float*)d_out;

    // workspace layout
    char* w = (char*)d_ws;
    const size_t ndf = (size_t)NN * DD * sizeof(float);
    unsigned short* Wt = (unsigned short*)w;  w += 4 * 16384 * sizeof(unsigned short);
    float* AX = (float*)w;                    w += ndf;
    float* EX = (float*)w;                    w += ndf;
    unsigned short* BD = (unsigned short*)w;  w += (size_t)NN * 256 * sizeof(unsigned short);
    float* H  = (float*)w;                    w += ndf;
    float* acc = (float*)w;                   w += 256 * sizeof(float);
    int* deg    = (int*)w;                    w += (size_t)NN * sizeof(int);
    int* off    = (int*)w;                    w += (size_t)(NN + 4) * sizeof(int);
    int* cursor = (int*)w;                    w += (size_t)NN * sizeof(int);
    int* bsum   = (int*)w;                    w += 64 * sizeof(int);
    int* bbase  = (int*)w;                    w += 64 * sizeof(int);
    int* srt    = (int*)w;                    w += (size_t)ne * sizeof(int);

    hipMemsetAsync(deg, 0, (size_t)NN * sizeof(int), stream);
    hipMemsetAsync(acc, 0, 256 * sizeof(float), stream);

    // weight prep + counting sort (independent of GEMM)
    prep_w<<<4, 256, 0, stream>>>(W_A, W_B, W_D, W_E, Wt);
    hist_k<<<(ne + 255) / 256, 256, 0, stream>>>(dst, deg, ne);
    partial_k<<<SCAN_NB, 1024, 0, stream>>>(deg, bsum);
    scanblk_k<<<1, 64, 0, stream>>>(bsum, bbase, off);
    offs_k<<<SCAN_NB, 1024, 0, stream>>>(deg, bbase, off, cursor);

    // fused 4-projection GEMM
    gemm4<<<(NN + 63) / 64, 256, 0, stream>>>(X, Wt, b_A, b_B, b_D, b_E, AX, EX, BD);

    scatter_k<<<(ne + 255) / 256, 256, 0, stream>>>(src, dst, cursor, srt, ne);

    // gate + aggregation + snorm (one wave per node)
    agg_k<<<NN / 4, 256, 0, stream>>>(AX, EX, (const uint2*)BD, X, off, srt, H);

    // BN stats
    bnstat_k<<<400, 256, 0, stream>>>(H, acc);

    // final
    final_k<<<(NN * 32 + 255) / 256, 256, 0, stream>>>(H, X, acc, gamma, beta, out);
}

// Round 4
// 330.567 us; speedup vs baseline: 1.7675x; 1.1953x over previous
//
#include <hip/hip_runtime.h>
#include <hip/hip_bf16.h>
#include <math.h>

#define NN 50000
#define DD 128
#define BN_EPS 1e-5f
#define SCAN_NB 49   // 49*1024 = 50176 >= NN

typedef short short8 __attribute__((ext_vector_type(8)));
typedef float f32x4 __attribute__((ext_vector_type(4)));

__device__ __forceinline__ unsigned short f2bf(float f) {
    __hip_bfloat16 h = __float2bfloat16(f);
    return *reinterpret_cast<unsigned short*>(&h);
}

// ---------------------------------------------------------------------------
// Prep: Wt[which][col][k] bf16 (transposed W), row-major 128x128 per which.
// ---------------------------------------------------------------------------
__global__ __launch_bounds__(256) void prep_w(
    const float* __restrict__ W0, const float* __restrict__ W1,
    const float* __restrict__ W2, const float* __restrict__ W3,
    unsigned short* __restrict__ Wt)
{
    const int which = blockIdx.x;
    const float* W = (which == 0) ? W0 : (which == 1) ? W1 : (which == 2) ? W2 : W3;
    unsigned short* O = Wt + (size_t)which * 16384;
    for (int it = 0; it < 8; ++it) {
        const int id = it * 256 + threadIdx.x;   // 0..2047
        const int col = id >> 4;                 // 0..127
        const int kc  = id & 15;                 // 0..15 (8 k each)
        unsigned int pk[4];
        #pragma unroll
        for (int p = 0; p < 4; ++p) {
            const float f0 = W[(kc * 8 + p * 2 + 0) * DD + col];
            const float f1 = W[(kc * 8 + p * 2 + 1) * DD + col];
            pk[p] = (unsigned int)f2bf(f0) | ((unsigned int)f2bf(f1) << 16);
        }
        uint4 v = make_uint4(pk[0], pk[1], pk[2], pk[3]);
        *(uint4*)(O + col * 128 + kc * 8) = v;
    }
}

// ---------------------------------------------------------------------------
// Fused 4-projection MFMA GEMM, 512 threads / 8 waves.
// Wave w: projection p = w>>1, column half h = w&1 (64 cols).
// Swapped operands: mfma(A=W^T frag, B=X^T frag) so each lane holds 4
// consecutive OUTPUT COLUMNS of one row -> wide epilogue stores.
// acc[4][4] = 64 VGPRs/wave -> high occupancy.
// BD row layout (shorts): group g (16B): [b(4g..4g+3) | d(4g..4g+3)]
// ---------------------------------------------------------------------------
__global__ __launch_bounds__(512, 4) void gemm4(
    const float* __restrict__ X, const unsigned short* __restrict__ Wt,
    const float* __restrict__ bA, const float* __restrict__ bB,
    const float* __restrict__ bD, const float* __restrict__ bE,
    float* __restrict__ AX, float* __restrict__ EX,
    unsigned short* __restrict__ BD)
{
    __shared__ char xs[64 * 256];   // 64 rows x 128 bf16, XOR-swizzled
    const int row0 = blockIdx.x * 64;
    const int tid  = threadIdx.x;

    // stage + convert X tile: 1024 16B-chunks, 2 per thread
    #pragma unroll
    for (int it = 0; it < 2; ++it) {
        const int idx = it * 512 + tid;     // 0..1023
        const int r = idx >> 4;             // 0..63
        const int c = idx & 15;             // 16B chunk in row
        const bool valid = (row0 + r) < NN;
        float4 va = make_float4(0.f, 0.f, 0.f, 0.f);
        float4 vb = make_float4(0.f, 0.f, 0.f, 0.f);
        if (valid) {
            const float* gp = X + (size_t)(row0 + r) * DD + c * 8;
            va = *(const float4*)(gp);
            vb = *(const float4*)(gp + 4);
        }
        uint4 pk;
        pk.x = (unsigned int)f2bf(va.x) | ((unsigned int)f2bf(va.y) << 16);
        pk.y = (unsigned int)f2bf(va.z) | ((unsigned int)f2bf(va.w) << 16);
        pk.z = (unsigned int)f2bf(vb.x) | ((unsigned int)f2bf(vb.y) << 16);
        pk.w = (unsigned int)f2bf(vb.z) | ((unsigned int)f2bf(vb.w) << 16);
        *(uint4*)(xs + r * 256 + ((c * 16) ^ ((r & 7) << 4))) = pk;
    }
    __syncthreads();

    const int wid  = tid >> 6;
    const int p    = wid >> 1;          // projection
    const int h    = wid & 1;           // column half
    const int lane = tid & 63;
    const int lr = lane & 15, lg = lane >> 4;

    f32x4 acc[4][4];
    #pragma unroll
    for (int m = 0; m < 4; ++m)
        #pragma unroll
        for (int n = 0; n < 4; ++n)
            acc[m][n] = (f32x4){0.f, 0.f, 0.f, 0.f};

    const char* wb = (const char*)(Wt + (size_t)p * 16384) + h * 64 * 256;

    #pragma unroll
    for (int k = 0; k < 4; ++k) {
        short8 aW[4];   // A-frag: rows = out-cols
        #pragma unroll
        for (int n = 0; n < 4; ++n)
            aW[n] = *(const short8*)(wb + (n * 16 + lr) * 256 + k * 64 + lg * 16);
        short8 bX[4];   // B-frag: cols = X-rows
        #pragma unroll
        for (int m = 0; m < 4; ++m)
            bX[m] = *(const short8*)(xs + (m * 16 + lr) * 256 +
                                     ((k * 64 + lg * 16) ^ ((lr & 7) << 4)));
        #pragma unroll
        for (int m = 0; m < 4; ++m)
            #pragma unroll
            for (int n = 0; n < 4; ++n)
                acc[m][n] = __builtin_amdgcn_mfma_f32_16x16x32_bf16(
                    aW[n], bX[m], acc[m][n], 0, 0, 0);
    }

    const float* bias = (p == 0) ? bA : (p == 1) ? bB : (p == 2) ? bD : bE;
    #pragma unroll
    for (int n = 0; n < 4; ++n) {
        const int cbase = h * 64 + n * 16 + lg * 4;   // 4 consecutive out-cols
        const float4 bv = *(const float4*)(bias + cbase);
        #pragma unroll
        for (int m = 0; m < 4; ++m) {
            const int row = row0 + m * 16 + lr;
            if (row < NN) {
                float v0 = acc[m][n][0] + bv.x;
                float v1 = acc[m][n][1] + bv.y;
                float v2 = acc[m][n][2] + bv.z;
                float v3 = acc[m][n][3] + bv.w;
                if (p == 0) {
                    *(float4*)(AX + (size_t)row * DD + cbase) = make_float4(v0, v1, v2, v3);
                } else if (p == 3) {
                    *(float4*)(EX + (size_t)row * DD + cbase) = make_float4(v0, v1, v2, v3);
                } else {
                    uint2 pk;
                    pk.x = (unsigned int)f2bf(v0) | ((unsigned int)f2bf(v1) << 16);
                    pk.y = (unsigned int)f2bf(v2) | ((unsigned int)f2bf(v3) << 16);
                    // group g = cbase/4, byte offset row*512 + g*16 (+8 for D)
                    char* dstp = (char*)BD + (size_t)row * 512 + (cbase >> 2) * 16
                               + ((p == 2) ? 8 : 0);
                    *(uint2*)dstp = pk;
                }
            }
        }
    }
}

// ---------------------------------------------------------------------------
// Counting sort of edges by dst
// ---------------------------------------------------------------------------
__global__ void hist_k(const int* __restrict__ dst, int* __restrict__ deg, int ne)
{
    const int e = blockIdx.x * blockDim.x + threadIdx.x;
    if (e < ne) atomicAdd(&deg[dst[e]], 1);
}

// 3-kernel scan
__global__ __launch_bounds__(1024) void partial_k(const int* __restrict__ deg,
                                                  int* __restrict__ bsum)
{
    __shared__ int ls[16];
    const int idx = blockIdx.x * 1024 + threadIdx.x;
    int v = (idx < NN) ? deg[idx] : 0;
    #pragma unroll
    for (int o = 1; o < 64; o <<= 1) v += __shfl_xor(v, o, 64);
    if ((threadIdx.x & 63) == 0) ls[threadIdx.x >> 6] = v;
    __syncthreads();
    if (threadIdx.x == 0) {
        int s = 0;
        #pragma unroll
        for (int i = 0; i < 16; ++i) s += ls[i];
        bsum[blockIdx.x] = s;
    }
}

__global__ __launch_bounds__(64) void scanblk_k(const int* __restrict__ bsum,
                                                int* __restrict__ bbase,
                                                int* __restrict__ off)
{
    const int t = threadIdx.x;
    int v = (t < SCAN_NB) ? bsum[t] : 0;
    const int orig = v;
    #pragma unroll
    for (int o = 1; o < 64; o <<= 1) {
        const int u = __shfl_up(v, o, 64);
        if (t >= o) v += u;
    }
    if (t < SCAN_NB) bbase[t] = v - orig;
    if (t == 63) off[NN] = v;
}

__global__ __launch_bounds__(1024) void offs_k(const int* __restrict__ deg,
                                               const int* __restrict__ bbase,
                                               int* __restrict__ off,
                                               int* __restrict__ cursor)
{
    __shared__ int ws[16];
    const int idx = blockIdx.x * 1024 + threadIdx.x;
    const int t = threadIdx.x;
    int v = (idx < NN) ? deg[idx] : 0;
    const int orig = v;
    #pragma unroll
    for (int o = 1; o < 64; o <<= 1) {
        const int u = __shfl_up(v, o, 64);
        if ((t & 63) >= o) v += u;
    }
    if ((t & 63) == 63) ws[t >> 6] = v;
    __syncthreads();
    int base = 0;
    for (int i = 0; i < (t >> 6); ++i) base += ws[i];
    const int ex = bbase[blockIdx.x] + base + (v - orig);
    if (idx < NN) { off[idx] = ex; cursor[idx] = ex; }
}

__global__ void scatter_k(const int* __restrict__ src, const int* __restrict__ dst,
                          int* __restrict__ cursor, int* __restrict__ srt, int ne)
{
    const int e = blockIdx.x * blockDim.x + threadIdx.x;
    if (e < ne) {
        const int p = atomicAdd(&cursor[dst[e]], 1);
        srt[p] = src[e];
    }
}

// ---------------------------------------------------------------------------
// Gate + weighted aggregation + snorm. One WAVE per node.
// Lanes 0..31 process edge i, lanes 32..63 edge i+1; 4 features/lane via
// one uint4 (=[b pair0, b pair1, d pair0, d pair1]); halves combined by
// shfl_xor(32) at the end.
// ---------------------------------------------------------------------------
__global__ __launch_bounds__(256) void agg_k(
    const float* __restrict__ AX, const float* __restrict__ EX,
    const uint4* __restrict__ BD4, const float* __restrict__ X,
    const int* __restrict__ off, const int* __restrict__ srt,
    float* __restrict__ H)
{
    const int wid  = threadIdx.x >> 6;
    const int lane = threadIdx.x & 63;
    const int half = lane >> 5;
    const int f    = lane & 31;          // feature group: features 4f..4f+3
    const int node = blockIdx.x * 4 + wid;
    const int beg = off[node], end = off[node + 1];

    const float4 ex = *(const float4*)(EX + (size_t)node * DD + f * 4);
    float num[4] = {0.f, 0.f, 0.f, 0.f};
    float den[4] = {0.f, 0.f, 0.f, 0.f};

#define EDGE4(wv)                                                            \
    {                                                                        \
        const float b0_ = __uint_as_float((wv).x << 16);                     \
        const float b1_ = __uint_as_float((wv).x & 0xffff0000u);             \
        const float b2_ = __uint_as_float((wv).y << 16);                     \
        const float b3_ = __uint_as_float((wv).y & 0xffff0000u);             \
        const float d0_ = __uint_as_float((wv).z << 16);                     \
        const float d1_ = __uint_as_float((wv).z & 0xffff0000u);             \
        const float d2_ = __uint_as_float((wv).w << 16);                     \
        const float d3_ = __uint_as_float((wv).w & 0xffff0000u);             \
        const float s0_ = 1.0f / (1.0f + __expf(-(d0_ + ex.x)));             \
        const float s1_ = 1.0f / (1.0f + __expf(-(d1_ + ex.y)));             \
        const float s2_ = 1.0f / (1.0f + __expf(-(d2_ + ex.z)));             \
        const float s3_ = 1.0f / (1.0f + __expf(-(d3_ + ex.w)));             \
        num[0] = fmaf(s0_, b0_, num[0]); den[0] += s0_;                      \
        num[1] = fmaf(s1_, b1_, num[1]); den[1] += s1_;                      \
        num[2] = fmaf(s2_, b2_, num[2]); den[2] += s2_;                      \
        num[3] = fmaf(s3_, b3_, num[3]); den[3] += s3_;                      \
    }

    int i = beg;
    for (; i + 8 <= end; i += 8) {       // 4 pairs = 8 edges in flight
        int ss[4];
        #pragma unroll
        for (int u = 0; u < 4; ++u) ss[u] = srt[i + 2 * u + half];
        uint4 wv[4];
        #pragma unroll
        for (int u = 0; u < 4; ++u) wv[u] = BD4[(size_t)ss[u] * 32 + f];
        #pragma unroll
        for (int u = 0; u < 4; ++u) EDGE4(wv[u]);
    }
    for (; i + 2 <= end; i += 2) {
        const int s = srt[i + half];
        const uint4 wv = BD4[(size_t)s * 32 + f];
        EDGE4(wv);
    }
    if (i < end && half == 0) {          // odd tail: lower half only
        const int s = srt[i];
        const uint4 wv = BD4[(size_t)s * 32 + f];
        EDGE4(wv);
    }
#undef EDGE4

    #pragma unroll
    for (int j = 0; j < 4; ++j) {
        num[j] += __shfl_xor(num[j], 32);
        den[j] += __shfl_xor(den[j], 32);
    }

    if (half == 0) {
        float4 hv;
        if (end > beg) {
            const float4 ax = *(const float4*)(AX + (size_t)node * DD + f * 4);
            hv.x = ax.x + num[0] / den[0];
            hv.y = ax.y + num[1] / den[1];
            hv.z = ax.z + num[2] / den[2];
            hv.w = ax.w + num[3] / den[3];
        } else {
            hv = *(const float4*)(X + (size_t)node * DD + f * 4);
        }
        hv.x *= (1.0f / NN); hv.y *= (1.0f / NN);
        hv.z *= (1.0f / NN); hv.w *= (1.0f / NN);
        *(float4*)(H + (size_t)node * DD + f * 4) = hv;
    }
}

// ---------------------------------------------------------------------------
// BatchNorm column stats
// ---------------------------------------------------------------------------
__global__ __launch_bounds__(256) void bnstat_k(const float* __restrict__ H,
                                                float* __restrict__ acc)
{
    __shared__ float l1[256], l2[256];
    const int t = threadIdx.x;
    const int f = t & 127, g = t >> 7;
    const int n0 = blockIdx.x * 125;
    float s1 = 0.f, s2 = 0.f;
    for (int r = g; r < 125; r += 2) {
        const float h = H[(size_t)(n0 + r) * DD + f];
        s1 += h;
        s2 += h * h;
    }
    l1[t] = s1; l2[t] = s2;
    __syncthreads();
    if (t < 128) {
        s1 = l1[t] + l1[t + 128];
        s2 = l2[t] + l2[t + 128];
        atomicAdd(&acc[f], s1);
        atomicAdd(&acc[128 + f], s2);
    }
}

// ---------------------------------------------------------------------------
// Final: out = X + relu(BN(H)), float4 per thread.
// ---------------------------------------------------------------------------
__global__ __launch_bounds__(256) void final_k(
    const float* __restrict__ H, const float* __restrict__ X,
    const float* __restrict__ acc,
    const float* __restrict__ gamma, const float* __restrict__ beta,
    float* __restrict__ out)
{
    const int i = blockIdx.x * 256 + threadIdx.x;
    if (i >= NN * 32) return;
    const int f = (i & 31) * 4;
    const float4 h = *(const float4*)(H + (size_t)i * 4);
    const float4 x = *(const float4*)(X + (size_t)i * 4);
    float4 o;
    #pragma unroll
    for (int c = 0; c < 4; ++c) {
        const float mean = acc[f + c] * (1.0f / NN);
        const float var  = acc[128 + f + c] * (1.0f / NN) - mean * mean;
        const float rstd = rsqrtf(var + BN_EPS);
        const float hv = (c == 0) ? h.x : (c == 1) ? h.y : (c == 2) ? h.z : h.w;
        const float xv = (c == 0) ? x.x : (c == 1) ? x.y : (c == 2) ? x.z : x.w;
        float v = (hv - mean) * rstd * gamma[f + c] + beta[f + c];
        v = fmaxf(v, 0.f);
        const float r = xv + v;
        if (c == 0) o.x = r; else if (c == 1) o.y = r; else if (c == 2) o.z = r; else o.w = r;
    }
    *(float4*)(out + (size_t)i * 4) = o;
}

// ---------------------------------------------------------------------------
extern "C" void kernel_launch(void* const* d_in, const int* in_sizes, int n_in,
                              void* d_out, int out_size, void* d_ws, size_t ws_size,
                              hipStream_t stream)
{
    const float* X     = (const float*)d_in[0];
    const float* W_A   = (const float*)d_in[1];
    const float* b_A   = (const float*)d_in[2];
    const float* W_B   = (const float*)d_in[3];
    const float* b_B   = (const float*)d_in[4];
    const float* W_D   = (const float*)d_in[5];
    const float* b_D   = (const float*)d_in[6];
    const float* W_E   = (const float*)d_in[7];
    const float* b_E   = (const float*)d_in[8];
    const float* gamma = (const float*)d_in[9];
    const float* beta  = (const float*)d_in[10];
    const int*   src   = (const int*)d_in[11];
    const int*   dst   = (const int*)d_in[12];
    const int    ne    = in_sizes[11];
    float* out = (float*)d_out;

    // workspace layout
    char* w = (char*)d_ws;
    const size_t ndf = (size_t)NN * DD * sizeof(float);
    unsigned short* Wt = (unsigned short*)w;  w += 4 * 16384 * sizeof(unsigned short);
    float* AX = (float*)w;                    w += ndf;
    float* EX = (float*)w;                    w += ndf;
    unsigned short* BD = (unsigned short*)w;  w += (size_t)NN * 256 * sizeof(unsigned short);
    float* H  = (float*)w;                    w += ndf;
    float* acc = (float*)w;                   w += 256 * sizeof(float);
    int* deg    = (int*)w;                    w += (size_t)NN * sizeof(int);
    int* off    = (int*)w;                    w += (size_t)(NN + 4) * sizeof(int);
    int* cursor = (int*)w;                    w += (size_t)NN * sizeof(int);
    int* bsum   = (int*)w;                    w += 64 * sizeof(int);
    int* bbase  = (int*)w;                    w += 64 * sizeof(int);
    int* srt    = (int*)w;                    w += (size_t)ne * sizeof(int);

    hipMemsetAsync(deg, 0, (size_t)NN * sizeof(int), stream);
    hipMemsetAsync(acc, 0, 256 * sizeof(float), stream);

    // weight prep + counting sort (independent of GEMM)
    prep_w<<<4, 256, 0, stream>>>(W_A, W_B, W_D, W_E, Wt);
    hist_k<<<(ne + 255) / 256, 256, 0, stream>>>(dst, deg, ne);
    partial_k<<<SCAN_NB, 1024, 0, stream>>>(deg, bsum);
    scanblk_k<<<1, 64, 0, stream>>>(bsum, bbase, off);
    offs_k<<<SCAN_NB, 1024, 0, stream>>>(deg, bbase, off, cursor);

    // fused 4-projection GEMM
    gemm4<<<(NN + 63) / 64, 512, 0, stream>>>(X, Wt, b_A, b_B, b_D, b_E, AX, EX, BD);

    scatter_k<<<(ne + 255) / 256, 256, 0, stream>>>(src, dst, cursor, srt, ne);

    // gate + aggregation + snorm (one wave per node)
    agg_k<<<NN / 4, 256, 0, stream>>>(AX, EX, (const uint4*)BD, X, off, srt, H);

    // BN stats
    bnstat_k<<<400, 256, 0, stream>>>(H, acc);

    // final
    final_k<<<(NN * 32 + 255) / 256, 256, 0, stream>>>(H, X, acc, gamma, beta, out);
}